// Round 5
// baseline (409.747 us; speedup 1.0000x reference)
//
#include <hip/hip_runtime.h>

#define HSZ   2048
#define NL    8
#define NBLK  2048            // 8 blocks/CU x 256 CUs — exact-fit co-residency
#define NTHR  256             // 4 waves: wave index == gate index
#define NGRP  64              // barrier arrival groups (padded lines)
#define BPG   (NBLK/NGRP)     // 32 arrivals per group
#define BAR_U32 1040          // per-barrier u32 stride: 64 groups*16 + master

// Native clang vector type: __builtin_nontemporal_load requires it
typedef float f4 __attribute__((ext_vector_type(4)));

// Relaxed agent-scope ops: compile to sc0/sc1 per-address-coherent accesses,
// NO buffer_wbl2 / buffer_inv cache maintenance (that was R3's ~30us/barrier).
__device__ __forceinline__ unsigned ld_rlx_u(const unsigned* p) {
    return __hip_atomic_load(p, __ATOMIC_RELAXED, __HIP_MEMORY_SCOPE_AGENT);
}
__device__ __forceinline__ float ld_rlx_f(const float* p) {
    return __hip_atomic_load(p, __ATOMIC_RELAXED, __HIP_MEMORY_SCOPE_AGENT);
}
__device__ __forceinline__ void st_rlx_f(float* p, float v) {
    __hip_atomic_store(p, v, __ATOMIC_RELAXED, __HIP_MEMORY_SCOPE_AGENT);
}
__device__ __forceinline__ void arrive(unsigned* bar, int grp) {
    unsigned o = __hip_atomic_fetch_add(&bar[grp * 16], 1u,
                    __ATOMIC_RELAXED, __HIP_MEMORY_SCOPE_AGENT);
    if (o == BPG - 1)   // last in group -> bump master
        __hip_atomic_fetch_add(&bar[NGRP * 16], 1u,
                    __ATOMIC_RELAXED, __HIP_MEMORY_SCOPE_AGENT);
}

// 8KB row dot: weights nontemporal (single-use stream), vector plain
// (LDS or L1/L2-cached global).
__device__ __forceinline__ float dot8(const f4* __restrict__ w,
                                      const f4* __restrict__ v, int lane) {
    float acc = 0.f;
    #pragma unroll
    for (int i = 0; i < 8; ++i) {
        f4 a = __builtin_nontemporal_load(&w[i * 64 + lane]);
        f4 b = v[i * 64 + lane];
        acc += a.x * b.x + a.y * b.y + a.z * b.z + a.w * b.w;
    }
    return acc;
}

// Block j owns output j. Wave w == gate w, row = w*H + j.
// Per layer: independent w_hh.h0[l] dot FIRST, then barrier-wait (hidden
// under it), then dependent w_ih.h dot.
__global__ __launch_bounds__(NTHR, 8) void lstm_fused(
    const float* __restrict__ x,
    const float* __restrict__ w_ih,   // [L,4H,H]
    const float* __restrict__ w_hh,   // [L,4H,H]
    const float* __restrict__ b_ih,   // [L,4H]
    const float* __restrict__ b_hh,   // [L,4H]
    const float* __restrict__ h0,     // [L,H]
    const float* __restrict__ c0,     // [L,H]
    float* __restrict__ out,          // [H]
    float* __restrict__ hA,           // ping
    float* __restrict__ hB,           // pong
    unsigned* __restrict__ bars)      // (NL-1)*BAR_U32 u32, pre-zeroed
{
    __shared__ float s_v[HSZ];
    __shared__ float s_g[4];

    const int tid  = threadIdx.x;
    const int wave = tid >> 6;        // gate 0..3 (i,f,g,o)
    const int lane = tid & 63;
    const int j    = blockIdx.x;
    const int row  = wave * HSZ + j;
    const int grp  = blockIdx.x & (NGRP - 1);

    // ---------------- layer 0 (fully independent) ----------------
    {
        const f4* x4 = (const f4*)x;
        f4* sv4 = (f4*)s_v;
        sv4[tid]        = x4[tid];
        sv4[tid + NTHR] = x4[tid + NTHR];
    }
    __syncthreads();

    {
        const float bs = b_ih[row] + b_hh[row];
        const f4* wi4 = (const f4*)(w_ih + (size_t)row * HSZ);
        const f4* wh4 = (const f4*)(w_hh + (size_t)row * HSZ);
        float acc = dot8(wi4, (const f4*)s_v, lane)
                  + dot8(wh4, (const f4*)h0, lane);
        #pragma unroll
        for (int off = 32; off; off >>= 1) acc += __shfl_down(acc, off, 64);
        if (lane == 0) s_g[wave] = acc + bs;
    }
    __syncthreads();
    if (tid == 0) {
        const float gi = s_g[0], gf = s_g[1], gg = s_g[2], go = s_g[3];
        const float si = 1.f / (1.f + __expf(-gi));
        const float sf = 1.f / (1.f + __expf(-gf));
        const float so = 1.f / (1.f + __expf(-go));
        const float cn = sf * c0[j] + si * tanhf(gg);
        st_rlx_f(&hA[j], tanhf(so * tanhf(cn)));   // h then inter-layer tanh
    }
    __syncthreads();                 // drain hbuf store before arrival
    if (tid == 0) arrive(bars, grp);

    // ---------------- layers 1..7 ----------------
    float* const hbufs[2] = { hA, hB };
    for (int l = 1; l < NL; ++l) {
        const size_t wof = ((size_t)l * 4 * HSZ + row) * HSZ;

        // independent half: w_hh[l] row . h0[l]  (hides the barrier wait)
        float acc2 = dot8((const f4*)(w_hh + wof),
                          (const f4*)(h0 + (size_t)l * HSZ), lane);
        const float bs = b_ih[(size_t)l * 4 * HSZ + row]
                       + b_hh[(size_t)l * 4 * HSZ + row];

        // wait for h of layer l-1
        const unsigned* mstr = &bars[(size_t)(l - 1) * BAR_U32 + NGRP * 16];
        if (tid == 0)
            while (ld_rlx_u(mstr) < NGRP) __builtin_amdgcn_s_sleep(8);
        __syncthreads();

        // stage h into LDS (coherent loads, lane-coalesced)
        const float* hin = hbufs[(l + 1) & 1];
        #pragma unroll
        for (int i = 0; i < 8; ++i)
            s_v[i * NTHR + tid] = ld_rlx_f(&hin[i * NTHR + tid]);
        __syncthreads();

        // dependent half: w_ih[l] row . h
        float acc = dot8((const f4*)(w_ih + wof), (const f4*)s_v, lane) + acc2;
        #pragma unroll
        for (int off = 32; off; off >>= 1) acc += __shfl_down(acc, off, 64);
        if (lane == 0) s_g[wave] = acc + bs;
        __syncthreads();

        if (tid == 0) {
            const float gi = s_g[0], gf = s_g[1], gg = s_g[2], go = s_g[3];
            const float si = 1.f / (1.f + __expf(-gi));
            const float sf = 1.f / (1.f + __expf(-gf));
            const float so = 1.f / (1.f + __expf(-go));
            const float cn = sf * c0[(size_t)l * HSZ + j] + si * tanhf(gg);
            const float h  = so * tanhf(cn);
            if (l < NL - 1) st_rlx_f(&hbufs[l & 1][j], tanhf(h));
            else            out[j] = h;               // last layer: no tanh
        }
        if (l < NL - 1) {
            __syncthreads();         // drain store before arrival
            if (tid == 0) arrive(bars + (size_t)l * BAR_U32, grp);
        }
    }
}

extern "C" void kernel_launch(void* const* d_in, const int* in_sizes, int n_in,
                              void* d_out, int out_size, void* d_ws, size_t ws_size,
                              hipStream_t stream) {
    const float* x    = (const float*)d_in[0];
    const float* w_ih = (const float*)d_in[1];
    const float* w_hh = (const float*)d_in[2];
    const float* b_ih = (const float*)d_in[3];
    const float* b_hh = (const float*)d_in[4];
    const float* h0   = (const float*)d_in[5];
    const float* c0   = (const float*)d_in[6];
    float* out = (float*)d_out;

    // ws: [bars (NL-1)*BAR_U32 u32][hA: H floats][hB: H floats]
    unsigned* bars = (unsigned*)d_ws;
    const size_t bars_bytes = (size_t)(NL - 1) * BAR_U32 * 4;
    float* hA = (float*)((char*)d_ws + ((bars_bytes + 255) & ~(size_t)255));
    float* hB = hA + HSZ;

    (void)hipMemsetAsync(bars, 0, bars_bytes, stream);
    lstm_fused<<<NBLK, NTHR, 0, stream>>>(
        x, w_ih, w_hh, b_ih, b_hh, h0, c0, out, hA, hB, bars);
}

// Round 6
// 280.429 us; speedup vs baseline: 1.4611x; 1.4611x over previous
//
#include <hip/hip_runtime.h>

#define HSZ   2048
#define NL    8
#define NBLK  1024            // 4 blocks/CU x 256 CUs — co-resident at VGPR<=128
#define NTHR  256             // 4 waves: wave index == gate index
#define NGRP  64              // barrier arrival groups (padded lines)
#define BPG   (NBLK/NGRP)     // 16 arrivals per group
#define BAR_U32 1040          // per-barrier u32 stride: 64 groups*16 + master

typedef float f4 __attribute__((ext_vector_type(4)));

// Relaxed agent-scope ops: per-address coherent (L3 point), no cache
// maintenance, no ordering ops. Data-ordering comes from __syncthreads'
// vmcnt(0) drain before the arrival RMW is issued.
__device__ __forceinline__ unsigned ld_rlx_u(const unsigned* p) {
    return __hip_atomic_load(p, __ATOMIC_RELAXED, __HIP_MEMORY_SCOPE_AGENT);
}
__device__ __forceinline__ float ld_rlx_f(const float* p) {
    return __hip_atomic_load(p, __ATOMIC_RELAXED, __HIP_MEMORY_SCOPE_AGENT);
}
__device__ __forceinline__ void st_rlx_f(float* p, float v) {
    __hip_atomic_store(p, v, __ATOMIC_RELAXED, __HIP_MEMORY_SCOPE_AGENT);
}
__device__ __forceinline__ void arrive(unsigned* bar, int grp) {
    unsigned o = __hip_atomic_fetch_add(&bar[grp * 16], 1u,
                    __ATOMIC_RELAXED, __HIP_MEMORY_SCOPE_AGENT);
    if (o == BPG - 1)
        __hip_atomic_fetch_add(&bar[NGRP * 16], 1u,
                    __ATOMIC_RELAXED, __HIP_MEMORY_SCOPE_AGENT);
}

// Two consecutive 8KB rows (w0, w0+HSZ) dotted against one shared vector.
// Plain cached loads (L2 works for us; weights stream once at full BW).
__device__ __forceinline__ void dot2(const f4* __restrict__ w0,
                                     const f4* __restrict__ v,
                                     int lane, float& acc0, float& acc1) {
    const f4* __restrict__ w1 = w0 + (HSZ / 4);
    #pragma unroll
    for (int i = 0; i < 8; ++i) {
        const int k = i * 64 + lane;
        f4 a0 = w0[k];
        f4 a1 = w1[k];
        f4 b  = v[k];
        acc0 += a0.x * b.x + a0.y * b.y + a0.z * b.z + a0.w * b.w;
        acc1 += a1.x * b.x + a1.y * b.y + a1.z * b.z + a1.w * b.w;
    }
}

// Block b owns outputs {2b, 2b+1}. Wave w == gate w, rows w*H+2b, w*H+2b+1.
// Per layer: independent w_hh.h0[l] dots FIRST, then barrier-wait (hidden
// under them), then dependent w_ih.h dots.
__global__ __launch_bounds__(NTHR, 4) void lstm_fused(
    const float* __restrict__ x,
    const float* __restrict__ w_ih,   // [L,4H,H]
    const float* __restrict__ w_hh,   // [L,4H,H]
    const float* __restrict__ b_ih,   // [L,4H]
    const float* __restrict__ b_hh,   // [L,4H]
    const float* __restrict__ h0,     // [L,H]
    const float* __restrict__ c0,     // [L,H]
    float* __restrict__ out,          // [H]
    float* __restrict__ hA,
    float* __restrict__ hB,
    unsigned* __restrict__ bars)      // (NL-1)*BAR_U32 u32, pre-zeroed
{
    __shared__ float s_v[HSZ];
    __shared__ float s_g[2][4];       // [jj][gate]

    const int tid  = threadIdx.x;
    const int wave = tid >> 6;        // gate 0..3 (i,f,g,o)
    const int lane = tid & 63;
    const int j0   = blockIdx.x * 2;  // this block's first output
    const int row  = wave * HSZ + j0; // first of two consecutive rows
    const int grp  = blockIdx.x & (NGRP - 1);

    // ---------------- layer 0 (fully independent) ----------------
    {
        const f4* x4 = (const f4*)x;
        f4* sv4 = (f4*)s_v;
        sv4[tid]        = x4[tid];
        sv4[tid + NTHR] = x4[tid + NTHR];
    }
    __syncthreads();

    {
        float a0 = 0.f, a1 = 0.f;
        dot2((const f4*)(w_ih + (size_t)row * HSZ), (const f4*)s_v, lane, a0, a1);
        dot2((const f4*)(w_hh + (size_t)row * HSZ), (const f4*)h0,  lane, a0, a1);
        #pragma unroll
        for (int off = 32; off; off >>= 1) {
            a0 += __shfl_down(a0, off, 64);
            a1 += __shfl_down(a1, off, 64);
        }
        if (lane == 0) {
            s_g[0][wave] = a0 + b_ih[row]     + b_hh[row];
            s_g[1][wave] = a1 + b_ih[row + 1] + b_hh[row + 1];
        }
    }
    __syncthreads();
    if (tid < 2) {
        const int jo = j0 + tid;
        const float gi = s_g[tid][0], gf = s_g[tid][1];
        const float gg = s_g[tid][2], go = s_g[tid][3];
        const float si = 1.f / (1.f + __expf(-gi));
        const float sf = 1.f / (1.f + __expf(-gf));
        const float so = 1.f / (1.f + __expf(-go));
        const float cn = sf * c0[jo] + si * tanhf(gg);
        st_rlx_f(&hA[jo], tanhf(so * tanhf(cn)));
    }
    __syncthreads();                  // drains the h store before arrival
    if (tid == 0) arrive(bars, grp);

    // ---------------- layers 1..7 ----------------
    float* const hbufs[2] = { hA, hB };
    for (int l = 1; l < NL; ++l) {
        const size_t wof = ((size_t)l * 4 * HSZ + row) * HSZ;
        const size_t bof = (size_t)l * 4 * HSZ + row;

        // independent half: w_hh rows . h0[l]  (hides the barrier wait)
        float a0 = 0.f, a1 = 0.f;
        dot2((const f4*)(w_hh + wof), (const f4*)(h0 + (size_t)l * HSZ),
             lane, a0, a1);

        // wait for h of layer l-1
        const unsigned* mstr = &bars[(size_t)(l - 1) * BAR_U32 + NGRP * 16];
        if (tid == 0)
            while (ld_rlx_u(mstr) < NGRP) __builtin_amdgcn_s_sleep(8);
        __syncthreads();

        // stage h into LDS (coherent dword loads, lane-coalesced)
        const float* hin = hbufs[(l + 1) & 1];
        #pragma unroll
        for (int i = 0; i < 8; ++i)
            s_v[i * NTHR + tid] = ld_rlx_f(&hin[i * NTHR + tid]);
        __syncthreads();

        // dependent half: w_ih rows . h
        dot2((const f4*)(w_ih + wof), (const f4*)s_v, lane, a0, a1);

        #pragma unroll
        for (int off = 32; off; off >>= 1) {
            a0 += __shfl_down(a0, off, 64);
            a1 += __shfl_down(a1, off, 64);
        }
        if (lane == 0) {
            s_g[0][wave] = a0 + b_ih[bof]     + b_hh[bof];
            s_g[1][wave] = a1 + b_ih[bof + 1] + b_hh[bof + 1];
        }
        __syncthreads();

        if (tid < 2) {
            const int jo = j0 + tid;
            const float gi = s_g[tid][0], gf = s_g[tid][1];
            const float gg = s_g[tid][2], go = s_g[tid][3];
            const float si = 1.f / (1.f + __expf(-gi));
            const float sf = 1.f / (1.f + __expf(-gf));
            const float so = 1.f / (1.f + __expf(-go));
            const float cn = sf * c0[(size_t)l * HSZ + jo] + si * tanhf(gg);
            const float h  = so * tanhf(cn);
            if (l < NL - 1) st_rlx_f(&hbufs[l & 1][jo], tanhf(h));
            else            out[jo] = h;             // last layer: no tanh
        }
        if (l < NL - 1) {
            __syncthreads();          // drain store before arrival
            if (tid == 0) arrive(bars + (size_t)l * BAR_U32, grp);
        }
    }
}

extern "C" void kernel_launch(void* const* d_in, const int* in_sizes, int n_in,
                              void* d_out, int out_size, void* d_ws, size_t ws_size,
                              hipStream_t stream) {
    const float* x    = (const float*)d_in[0];
    const float* w_ih = (const float*)d_in[1];
    const float* w_hh = (const float*)d_in[2];
    const float* b_ih = (const float*)d_in[3];
    const float* b_hh = (const float*)d_in[4];
    const float* h0   = (const float*)d_in[5];
    const float* c0   = (const float*)d_in[6];
    float* out = (float*)d_out;

    unsigned* bars = (unsigned*)d_ws;
    const size_t bars_bytes = (size_t)(NL - 1) * BAR_U32 * 4;
    float* hA = (float*)((char*)d_ws + ((bars_bytes + 255) & ~(size_t)255));
    float* hB = hA + HSZ;

    (void)hipMemsetAsync(bars, 0, bars_bytes, stream);
    lstm_fused<<<NBLK, NTHR, 0, stream>>>(
        x, w_ih, w_hh, b_ih, b_hh, h0, c0, out, hA, hB, bars);
}